// Round 3
// baseline (142.758 us; speedup 1.0000x reference)
//
#include <hip/hip_runtime.h>

// LPC synthesis (AR(15), frame-hopped coefs) + de-emphasis IIR.
// Truncated-history recomputation, one output frame per lane, 3-frame
// (240-sample) warm-up. De-emph truncation 0.97^240*|z|max ~ 1.5e-2 vs
// threshold 4.56e-2.
//
// R9: COALESCED OUTPUT VIA LDS. R8 proved the scattered store pattern
// (16 B/lane at 320 B lane stride) only works at LOW occupancy: at 2
// blocks/CU L2 assembles full lines (R6: WRITE 64 MB), at 6 blocks/CU the
// partial-line streams thrash L2 and HBM write traffic explodes to 165 MB
// (output is 61 MB) -> write-amplification-bound at 87 us, VALUBusy 28%.
// Fix: emit pass converts z to fp16 and writes it back IN PLACE into the
// lane's own excit LDS slot (same-lane RAW, no barrier needed inside the
// pass); a final cooperative phase stores the block's 125 contiguous
// frames as lane-consecutive float4s -- every wave store is a full
// contiguous 1 KB burst, zero line assembly required, at ANY occupancy.
// Two extra barriers: before emit pass (wave 1 warm-up still reads slot 63
// while wave 0 would overwrite it) and before the store phase.
// Precision: fp16 z staging adds ~1.5e-3 (|z|<~3) on top of 1.56e-2
// truncation + ~2e-4 fp16 excit staging; total ~0.018 << 0.0456.
// R8 lessons kept: fp16 excit staging (21.5 KB LDS -> ~6 blocks/CU),
// taps straight from global with fmaf(-a,..) neg-modifier folding,
// g<=0 state reset. R3 lesson kept: no big per-lane arrays.

namespace {
constexpr int kFS = 80;        // frame shift
constexpr int kF = 3000;       // frames per batch
constexpr int kL = kFS * kF;   // 240000
constexpr int kOrder = 16;
constexpr int kB = 64;
constexpr float kEmph = 0.97f;
constexpr int kThreads = 128;          // 2 waves/block
constexpr int kEmit = kThreads - 3;    // 125 emit frames per block
constexpr int kSE = 84;                // fp16 LDS stride (halves), 168 B
constexpr int kV4 = kEmit * kFS / 4;   // 2500 float4s of output per block

typedef float vfloat4 __attribute__((ext_vector_type(4)));
typedef _Float16 half4v __attribute__((ext_vector_type(4)));
}  // namespace

__global__ __launch_bounds__(kThreads) void lpc_synth_kernel(
    const float* __restrict__ excit, const float* __restrict__ coef,
    float* __restrict__ out) {
  __shared__ _Float16 s_e[kThreads * kSE];  // 21504 B

  const int tid = threadIdx.x;
  const int b = blockIdx.y;
  const int fbase = blockIdx.x * kEmit;
  const int Lf = fbase - 3 + tid;  // frame this lane stages == emits
  const int Lc = min(max(Lf, 0), kF - 1);

  const float* __restrict__ ebase = excit + (size_t)b * kL;
  const float* __restrict__ cbase = coef + (size_t)b * kF * kOrder;

  // ---- Stage own excitation frame as fp16 (20 x 16B loads -> 8B writes).
  {
    const vfloat4* __restrict__ ep =
        (const vfloat4*)(ebase + (size_t)Lc * kFS);
    half4v* se = (half4v*)(s_e + tid * kSE);
#pragma unroll
    for (int j = 0; j < 20; ++j) {
      const vfloat4 v = ep[j];
      half4v h;
      h.x = (_Float16)v.x;
      h.y = (_Float16)v.y;
      h.z = (_Float16)v.z;
      h.w = (_Float16)v.w;
      se[j] = h;
    }
  }
  __syncthreads();

  // Ring buffer of last 16 y-samples (slot = n mod 16; 80%16==0 keeps frame
  // starts aligned). Compile-time indexed -> VGPRs.
  float x[16];
#pragma unroll
  for (int i = 0; i < 16; ++i) x[i] = 0.f;
  float z = 0.f;

  // One frame pass. g may be <0 for junk/warm-up lanes: the g<=0 reset
  // makes the g==0 pass start from the true zero state, so frames 0..2
  // are exact (up to fp16 noise) and junk passes are harmless.
  // Taps consumed as -a_[k] via the fmaf neg source modifier (zero cost).
  // EMIT_WB: write z back (fp16) into this lane's OWN slot, in place --
  // the value read at j is consumed before the write at j (same lane).
#define FRAME_BODY(T, EMIT_WB)                                             \
  {                                                                        \
    const int g = Lf - 3 + (T);                                            \
    const int gc = min(max(g, 0), kF - 1);                                 \
    const int slot = max(tid - 3 + (T), 0);                                \
    if (g <= 0) {                                                          \
      _Pragma("unroll") for (int i = 0; i < 16; ++i) x[i] = 0.f;           \
      z = 0.f;                                                             \
    }                                                                      \
    const vfloat4* __restrict__ cp =                                       \
        (const vfloat4*)(cbase + (size_t)gc * kOrder);                     \
    const vfloat4 c0 = cp[0], c1 = cp[1], c2 = cp[2], c3 = cp[3];          \
    const float a_[15] = {c0.y, c0.z, c0.w, c1.x, c1.y, c1.z, c1.w,        \
                          c2.x, c2.y, c2.z, c2.w, c3.x, c3.y, c3.z, c3.w}; \
    half4v* __restrict__ ses = (half4v*)(s_e + slot * kSE);                \
    _Pragma("unroll") for (int j = 0; j < 20; ++j) {                       \
      const half4v h = ses[j];                                             \
      float f_[4];                                                         \
      f_[0] = (float)h.x;                                                  \
      f_[1] = (float)h.y;                                                  \
      f_[2] = (float)h.z;                                                  \
      f_[3] = (float)h.w;                                                  \
      half4v ho;                                                           \
      _Pragma("unroll") for (int q = 0; q < 4; ++q) {                      \
        const int s = 4 * j + q;                                           \
        /* 3 partial accumulators: cross-sample critical path is */        \
        /* 1 fma + 1 add (8 cyc) vs ~38 cyc of issue. */                   \
        float a0 = f_[q];                                                  \
        a0 = fmaf(-a_[14], x[(s - 15) & 15], a0);                          \
        a0 = fmaf(-a_[13], x[(s - 14) & 15], a0);                          \
        a0 = fmaf(-a_[12], x[(s - 13) & 15], a0);                          \
        a0 = fmaf(-a_[11], x[(s - 12) & 15], a0);                          \
        a0 = fmaf(-a_[10], x[(s - 11) & 15], a0);                          \
        float a1 = -a_[9] * x[(s - 10) & 15];                              \
        a1 = fmaf(-a_[8], x[(s - 9) & 15], a1);                            \
        a1 = fmaf(-a_[7], x[(s - 8) & 15], a1);                            \
        a1 = fmaf(-a_[6], x[(s - 7) & 15], a1);                            \
        a1 = fmaf(-a_[5], x[(s - 6) & 15], a1);                            \
        float a2 = -a_[4] * x[(s - 5) & 15];                               \
        a2 = fmaf(-a_[3], x[(s - 4) & 15], a2);                            \
        a2 = fmaf(-a_[2], x[(s - 3) & 15], a2);                            \
        a2 = fmaf(-a_[1], x[(s - 2) & 15], a2);                            \
        const float a01 = a0 + a1;              /* off critical path */    \
        a2 = fmaf(-a_[0], x[(s - 1) & 15], a2); /* critical: 1 fma */      \
        const float acc = a01 + a2;             /* + 1 add */              \
        x[s & 15] = acc;                                                   \
        z = fmaf(kEmph, z, acc); /* de-emphasis IIR */                     \
        if (EMIT_WB) {                                                     \
          if (q == 0) ho.x = (_Float16)z;                                  \
          if (q == 1) ho.y = (_Float16)z;                                  \
          if (q == 2) ho.z = (_Float16)z;                                  \
          if (q == 3) ho.w = (_Float16)z;                                  \
        }                                                                  \
      }                                                                    \
      if (EMIT_WB) ses[j] = ho; /* in-place: own slot, post-read */        \
    }                                                                      \
  }

#pragma unroll 1
  for (int t = 0; t < 3; ++t) {
    FRAME_BODY(t, false)  // warm-up frames
  }
  // Cross-wave hazard: wave 1's warm-up reads slots 61..63 while wave 0's
  // emit pass overwrites them. Fence before any in-place writes.
  __syncthreads();
  FRAME_BODY(3, true)  // emit frame, z written back into own slot (fp16)
#undef FRAME_BODY
  __syncthreads();

  // ---- Coalesced store: 125 contiguous frames = 2500 float4s per block.
  // Lane-consecutive addresses -> each wave store is a contiguous 1 KB
  // burst; no L2 line assembly needed at any occupancy (the R8 failure).
  {
    vfloat4* __restrict__ ob = (vfloat4*)(out + (size_t)b * kL +
                                          (size_t)fbase * kFS);
#pragma unroll 1
    for (int i = tid; i < kV4; i += kThreads) {
      const int k = i / 20;   // frame within block (0..124) -> slot k+3
      const int j = i % 20;   // float4 within frame
      const half4v h = *(const half4v*)(s_e + (k + 3) * kSE + 4 * j);
      vfloat4 v;
      v.x = (float)h.x;
      v.y = (float)h.y;
      v.z = (float)h.z;
      v.w = (float)h.w;
      ob[i] = v;
    }
  }
}

extern "C" void kernel_launch(void* const* d_in, const int* in_sizes, int n_in,
                              void* d_out, int out_size, void* d_ws,
                              size_t ws_size, hipStream_t stream) {
  const float* excit = (const float*)d_in[0];  // (B, L, 1) fp32
  const float* coef = (const float*)d_in[1];   // (B, F, 16) fp32
  float* out = (float*)d_out;                  // (B, L, 1) fp32

  dim3 grid((kF + kEmit - 1) / kEmit, kB);  // 24 x 64 blocks of 128
  lpc_synth_kernel<<<grid, kThreads, 0, stream>>>(excit, coef, out);
}

// Round 4
// 128.968 us; speedup vs baseline: 1.1069x; 1.1069x over previous
//
#include <hip/hip_runtime.h>

// LPC synthesis (AR(15), frame-hopped coefs) + de-emphasis IIR.
//
// R10: SCAN-CORRECTED DE-EMPHASIS -> warm-up 3 frames -> 1 frame.
// The 3-frame warm-up existed only for the de-emph IIR (0.97^240 ~ 6.7e-4
// truncation); the AR recursion itself converges in <1 frame (taps tiny:
// worst root radius ~0.86 -> 0.86^80 ~ 1e-5). De-emph is a LINEAR scalar
// IIR, so the missing init is patched post-hoc:
//   z_exact[s] = z_loc[s] + 0.97^(81+s) * z_end(frame-2)
// where z_end(frame-2) is lane (tid-2)'s own local end-state, exchanged
// via 512 B of LDS, with a one-link refinement
//   C(k) = zend[k+1] + 0.97^160 * zend[k-1]   (residual ~1e-5, negligible;
// k=0 lanes keep exactly the old 0.97^241 truncation). Correction is folded
// into the coalesced store phase: 1 exp2f + 4 fma per 16 output samples.
// Result: 2 passes/sample instead of 4 -> ALU work halves.
//
// Kept from R9: coalesced output via in-place fp16 z writeback + LDS store
// phase (R8 proved scattered 16B/lane stores write-amplify 2.6x at high
// occupancy; R9 measured WRITE 60 MB = ideal). Kept from R8: fp16 excit
// staging (21.5 KB -> ~6-7 blocks/CU; R5's 51.7 KB capped at 12% occupancy),
// taps straight from global with fmaf(-a,..) neg-modifier folding, g<=0
// state reset for exactness at signal start. R3: no big per-lane arrays.
// absmax history: 0.0156 (R6..R9, truncation-dominated) vs threshold 0.0456.

namespace {
constexpr int kFS = 80;        // frame shift
constexpr int kF = 3000;       // frames per batch
constexpr int kL = kFS * kF;   // 240000
constexpr int kOrder = 16;
constexpr int kB = 64;
constexpr float kEmph = 0.97f;
constexpr int kThreads = 128;          // 2 waves/block
constexpr int kEmit = kThreads - 3;    // 125 emit frames per block
constexpr int kSE = 84;                // fp16 LDS stride (halves), 168 B
constexpr int kV4 = kEmit * kFS / 4;   // 2500 float4s of output per block
constexpr float kMu = 7.6471e-3f;      // 0.97^160 (one 2-frame link)
constexpr float kLg97 = -4.3943347e-2f;  // log2(0.97)

typedef float vfloat4 __attribute__((ext_vector_type(4)));
typedef _Float16 half4v __attribute__((ext_vector_type(4)));
}  // namespace

__global__ __launch_bounds__(kThreads) void lpc_synth_kernel(
    const float* __restrict__ excit, const float* __restrict__ coef,
    float* __restrict__ out) {
  __shared__ _Float16 s_e[kThreads * kSE];  // 21504 B
  __shared__ float s_zend[kThreads];        //   512 B: local de-emph ends

  const int tid = threadIdx.x;
  const int b = blockIdx.y;
  const int fbase = blockIdx.x * kEmit;
  const int Lf = fbase - 3 + tid;  // frame this lane stages == emits
  const int Lc = min(max(Lf, 0), kF - 1);
  const bool emit = (tid >= 3);    // grid is exact: Lf < kF always

  const float* __restrict__ ebase = excit + (size_t)b * kL;
  const float* __restrict__ cbase = coef + (size_t)b * kF * kOrder;

  // ---- Stage own excitation frame as fp16 (20 x 16B loads -> 8B writes).
  {
    const vfloat4* __restrict__ ep =
        (const vfloat4*)(ebase + (size_t)Lc * kFS);
    half4v* se = (half4v*)(s_e + tid * kSE);
#pragma unroll
    for (int j = 0; j < 20; ++j) {
      const vfloat4 v = ep[j];
      half4v h;
      h.x = (_Float16)v.x;
      h.y = (_Float16)v.y;
      h.z = (_Float16)v.z;
      h.w = (_Float16)v.w;
      se[j] = h;
    }
  }
  __syncthreads();

  // Ring buffer of last 16 y-samples (slot = n mod 16; 80%16==0 keeps frame
  // starts aligned). Compile-time indexed -> VGPRs.
  float x[16];
#pragma unroll
  for (int i = 0; i < 16; ++i) x[i] = 0.f;
  float z = 0.f;

  // One frame pass. T=0: warm-up on frame Lf-1 (slot tid-1); T=1: emit on
  // frame Lf (slot tid). g<=0 reset => frames 0,1 computed from the true
  // zero state (signal start), junk passes harmless. Taps consumed as
  // -a_[k] via the fmaf neg source modifier (zero cost). EMIT_WB: z written
  // back fp16 into own slot, in place (same-lane RAW: read-before-write).
#define FRAME_BODY(T, EMIT_WB)                                             \
  {                                                                        \
    const int g = Lf - 1 + (T);                                            \
    const int gc = min(max(g, 0), kF - 1);                                 \
    const int slot = max(tid - 1 + (T), 0);                                \
    if (g <= 0) {                                                          \
      _Pragma("unroll") for (int i = 0; i < 16; ++i) x[i] = 0.f;           \
      z = 0.f;                                                             \
    }                                                                      \
    const vfloat4* __restrict__ cp =                                       \
        (const vfloat4*)(cbase + (size_t)gc * kOrder);                     \
    const vfloat4 c0 = cp[0], c1 = cp[1], c2 = cp[2], c3 = cp[3];          \
    const float a_[15] = {c0.y, c0.z, c0.w, c1.x, c1.y, c1.z, c1.w,        \
                          c2.x, c2.y, c2.z, c2.w, c3.x, c3.y, c3.z, c3.w}; \
    half4v* __restrict__ ses = (half4v*)(s_e + slot * kSE);                \
    _Pragma("unroll") for (int j = 0; j < 20; ++j) {                       \
      const half4v h = ses[j];                                             \
      float f_[4];                                                         \
      f_[0] = (float)h.x;                                                  \
      f_[1] = (float)h.y;                                                  \
      f_[2] = (float)h.z;                                                  \
      f_[3] = (float)h.w;                                                  \
      half4v ho;                                                           \
      _Pragma("unroll") for (int q = 0; q < 4; ++q) {                      \
        const int s = 4 * j + q;                                           \
        /* 3 partial accumulators: cross-sample critical path is */        \
        /* 1 fma + 1 add (8 cyc) vs ~38 cyc of issue. */                   \
        float a0 = f_[q];                                                  \
        a0 = fmaf(-a_[14], x[(s - 15) & 15], a0);                          \
        a0 = fmaf(-a_[13], x[(s - 14) & 15], a0);                          \
        a0 = fmaf(-a_[12], x[(s - 13) & 15], a0);                          \
        a0 = fmaf(-a_[11], x[(s - 12) & 15], a0);                          \
        a0 = fmaf(-a_[10], x[(s - 11) & 15], a0);                          \
        float a1 = -a_[9] * x[(s - 10) & 15];                              \
        a1 = fmaf(-a_[8], x[(s - 9) & 15], a1);                            \
        a1 = fmaf(-a_[7], x[(s - 8) & 15], a1);                            \
        a1 = fmaf(-a_[6], x[(s - 7) & 15], a1);                            \
        a1 = fmaf(-a_[5], x[(s - 6) & 15], a1);                            \
        float a2 = -a_[4] * x[(s - 5) & 15];                               \
        a2 = fmaf(-a_[3], x[(s - 4) & 15], a2);                            \
        a2 = fmaf(-a_[2], x[(s - 3) & 15], a2);                            \
        a2 = fmaf(-a_[1], x[(s - 2) & 15], a2);                            \
        const float a01 = a0 + a1;              /* off critical path */    \
        a2 = fmaf(-a_[0], x[(s - 1) & 15], a2); /* critical: 1 fma */      \
        const float acc = a01 + a2;             /* + 1 add */              \
        x[s & 15] = acc;                                                   \
        z = fmaf(kEmph, z, acc); /* de-emphasis IIR (local init) */        \
        if (EMIT_WB) {                                                     \
          if (q == 0) ho.x = (_Float16)z;                                  \
          if (q == 1) ho.y = (_Float16)z;                                  \
          if (q == 2) ho.z = (_Float16)z;                                  \
          if (q == 3) ho.w = (_Float16)z;                                  \
        }                                                                  \
      }                                                                    \
      if (EMIT_WB) ses[j] = ho; /* in-place: own slot, post-read */        \
    }                                                                      \
  }

  FRAME_BODY(0, false)  // single AR warm-up frame (Lf-1)
  // Hazard: lane i+1's warm-up reads slot i, which lane i's emit pass
  // overwrites. Fence before any in-place writes.
  __syncthreads();
  FRAME_BODY(1, emit)  // emit frame: z_loc written back into own slot
#undef FRAME_BODY
  s_zend[tid] = z;  // local de-emph end state (covers frames Lf-1..Lf)
  __syncthreads();

  // ---- Coalesced store + de-emph init correction.
  // Frame k (block-local) was emitted by lane k+3; its z_loc is missing
  // 0.97^(81+s) * z_end(frame fbase+k-2). That state is approximated by
  //   C = s_zend[k+1] + kMu * s_zend[k-1]          (kMu = 0.97^160)
  // with guards so frames before signal start contribute 0 (block 0) and
  // k=0 falls back to exactly the old 3-frame truncation accuracy.
  {
    vfloat4* __restrict__ ob = (vfloat4*)(out + (size_t)b * kL +
                                          (size_t)fbase * kFS);
#pragma unroll 1
    for (int i = tid; i < kV4; i += kThreads) {
      const int k = i / 20;   // frame within block (0..124) -> slot k+3
      const int j = i % 20;   // float4 within frame
      const half4v h = *(const half4v*)(s_e + (k + 3) * kSE + 4 * j);
      float C = 0.f;
      if (fbase + k - 2 >= 0) C = s_zend[k + 1];
      if (k >= 1 && fbase + k - 4 >= 0) C = fmaf(kMu, s_zend[k - 1], C);
      const float e0 = __builtin_exp2f(kLg97 * (float)(81 + 4 * j));
      vfloat4 v;
      v.x = fmaf(e0, C, (float)h.x);
      v.y = fmaf(e0 * 0.97f, C, (float)h.y);
      v.z = fmaf(e0 * 0.9409f, C, (float)h.z);
      v.w = fmaf(e0 * 0.912673f, C, (float)h.w);
      ob[i] = v;  // lane-consecutive float4s: full 1 KB bursts per wave
    }
  }
}

extern "C" void kernel_launch(void* const* d_in, const int* in_sizes, int n_in,
                              void* d_out, int out_size, void* d_ws,
                              size_t ws_size, hipStream_t stream) {
  const float* excit = (const float*)d_in[0];  // (B, L, 1) fp32
  const float* coef = (const float*)d_in[1];   // (B, F, 16) fp32
  float* out = (float*)d_out;                  // (B, L, 1) fp32

  dim3 grid((kF + kEmit - 1) / kEmit, kB);  // 24 x 64 blocks of 128
  lpc_synth_kernel<<<grid, kThreads, 0, stream>>>(excit, coef, out);
}

// Round 5
// 126.865 us; speedup vs baseline: 1.1253x; 1.0166x over previous
//
#include <hip/hip_runtime.h>

// LPC synthesis (AR(15), frame-hopped coefs) + de-emphasis IIR.
//
// R11: SHORTER AR WARM-UP + SINGLE-FRAME zf CORRECTION + TAP HOIST.
// R10 measured: 45.5 us, VALU-busy ~15 us, occupancy 20% -> stall-bound.
// Changes:
//  - Warm-up is AR-ONLY and 48 samples (zero state at sample 32 of frame
//    Lf-1). AR truncation ~rho^48 (~2e-5 at typical rho~0.8). z no longer
//    tracked in warm-up.
//  - z covers ONLY the emit frame (z=0 at frame start). Missing init
//    patched in the store phase: z += 0.97^(s+1) * Zprev with
//      Zprev = zf[k+3] + r*zf[k+2] + r^2*zf[k+1] + r^3*zf[k],  r=0.97^80
//    4 junk lanes (kEmit=124) make all 4 terms exist for every frame ->
//    truncation floor r^4*|Z|max ~ 1.3e-3 (was 1.5e-2 for k=0 lanes).
//  - Both tap loads (warm + emit frame) hoisted before staging: their
//    vmcnt completes under the staging+barrier shadow, removing the
//    dependent-load stall at the head of each pass.
// Error budget: fp16 z-writeback ~1e-2 (|z|max~22) + correction ~1.3e-3 +
// fp16 excit ~2e-3 + AR trunc ~1e-3 => ~0.016-0.035 vs threshold 0.0456.
//
// Kept: R9 coalesced output via in-place fp16 z writeback + LDS store
// phase (R8: scattered 16B/lane stores write-amplify 2.6x at occupancy);
// R8 fp16 excit staging (21.5 KB -> ~7 blocks/CU; 43 KB capped at 12%),
// fmaf(-a,..) neg-modifier tap folding; R7 g<=0 state reset; R3 no big
// per-lane arrays. 3 barriers: stage->warmup (cross-lane LDS), warmup->
// emit (lane64 reads slot63 before its writeback), emit->store.

namespace {
constexpr int kFS = 80;        // frame shift
constexpr int kF = 3000;       // frames per batch
constexpr int kL = kFS * kF;   // 240000
constexpr int kOrder = 16;
constexpr int kB = 64;
constexpr float kEmph = 0.97f;
constexpr int kThreads = 128;          // 2 waves/block
constexpr int kEmit = kThreads - 4;    // 124 emit frames per block
constexpr int kSE = 84;                // fp16 LDS stride (halves), 168 B
constexpr float kR1 = 0.08744575f;     // 0.97^80
constexpr float kR2 = 0.00764676f;     // 0.97^160
constexpr float kR3 = 6.6872537e-4f;   // 0.97^240
constexpr float kLg97 = -4.3943347e-2f;  // log2(0.97)

typedef float vfloat4 __attribute__((ext_vector_type(4)));
typedef _Float16 half4v __attribute__((ext_vector_type(4)));
}  // namespace

__global__ __launch_bounds__(kThreads) void lpc_synth_kernel(
    const float* __restrict__ excit, const float* __restrict__ coef,
    float* __restrict__ out) {
  __shared__ _Float16 s_e[kThreads * kSE];  // 21504 B
  __shared__ float s_zend[kThreads];        //   512 B: per-lane zf

  const int tid = threadIdx.x;
  const int b = blockIdx.y;
  const int fbase = blockIdx.x * kEmit;
  const int Lf = fbase - 4 + tid;  // frame this lane stages == emits
  const int Lc = min(max(Lf, 0), kF - 1);
  const int Lw = min(max(Lf - 1, 0), kF - 1);  // warm-up frame (clamped)

  const float* __restrict__ ebase = excit + (size_t)b * kL;
  const float* __restrict__ cbase = coef + (size_t)b * kF * kOrder;

  // ---- Hoisted tap loads: warm-frame + emit-frame taps issued FIRST so
  // their latency is covered by the staging loads + barrier below.
  const vfloat4* __restrict__ cw =
      (const vfloat4*)(cbase + (size_t)Lw * kOrder);
  const vfloat4* __restrict__ ce =
      (const vfloat4*)(cbase + (size_t)Lc * kOrder);
  const vfloat4 w0 = cw[0], w1 = cw[1], w2 = cw[2], w3 = cw[3];
  const vfloat4 e0 = ce[0], e1 = ce[1], e2 = ce[2], e3 = ce[3];

  // ---- Stage own excitation frame as fp16 (20 x 16B loads -> 8B writes).
  {
    const vfloat4* __restrict__ ep =
        (const vfloat4*)(ebase + (size_t)Lc * kFS);
    half4v* se = (half4v*)(s_e + tid * kSE);
#pragma unroll
    for (int j = 0; j < 20; ++j) {
      const vfloat4 v = ep[j];
      half4v h;
      h.x = (_Float16)v.x;
      h.y = (_Float16)v.y;
      h.z = (_Float16)v.z;
      h.w = (_Float16)v.w;
      se[j] = h;
    }
  }
  __syncthreads();

  // Ring buffer of last 16 y-samples (slot = n mod 16; warm-up starts at
  // sample 32, 32%16==0 keeps alignment). Compile-time indexed -> VGPRs.
  float x[16];
#pragma unroll
  for (int i = 0; i < 16; ++i) x[i] = 0.f;

  // One AR sample; 3 partial accumulators keep the cross-sample critical
  // path at 1 fma + 1 add (8 cyc) vs ~36 cyc of issue. Taps consumed as
  // -a_[k] via the fmaf neg source modifier (zero cost).
#define AR_SAMPLE(s, e_in, ACC)                                            \
  float ACC;                                                               \
  {                                                                        \
    float a0 = (e_in);                                                     \
    a0 = fmaf(-a_[14], x[((s)-15) & 15], a0);                              \
    a0 = fmaf(-a_[13], x[((s)-14) & 15], a0);                              \
    a0 = fmaf(-a_[12], x[((s)-13) & 15], a0);                              \
    a0 = fmaf(-a_[11], x[((s)-12) & 15], a0);                              \
    a0 = fmaf(-a_[10], x[((s)-11) & 15], a0);                              \
    float a1 = -a_[9] * x[((s)-10) & 15];                                  \
    a1 = fmaf(-a_[8], x[((s)-9) & 15], a1);                                \
    a1 = fmaf(-a_[7], x[((s)-8) & 15], a1);                                \
    a1 = fmaf(-a_[6], x[((s)-7) & 15], a1);                                \
    a1 = fmaf(-a_[5], x[((s)-6) & 15], a1);                                \
    float a2 = -a_[4] * x[((s)-5) & 15];                                   \
    a2 = fmaf(-a_[3], x[((s)-4) & 15], a2);                                \
    a2 = fmaf(-a_[2], x[((s)-3) & 15], a2);                                \
    a2 = fmaf(-a_[1], x[((s)-2) & 15], a2);                                \
    const float a01 = a0 + a1;               /* off critical path */       \
    a2 = fmaf(-a_[0], x[((s)-1) & 15], a2);  /* critical: 1 fma */         \
    ACC = a01 + a2;                          /* + 1 add */                 \
    x[(s)&15] = ACC;                                                       \
  }

  // ---- AR-only warm-up: last 48 samples of frame Lf-1 (slot tid-1).
  {
    const int wslot = max(tid - 1, 0);
    const half4v* __restrict__ ses = (const half4v*)(s_e + wslot * kSE);
    const float a_[15] = {w0.y, w0.z, w0.w, w1.x, w1.y, w1.z, w1.w,
                          w2.x, w2.y, w2.z, w2.w, w3.x, w3.y, w3.z, w3.w};
#pragma unroll
    for (int j = 8; j < 20; ++j) {
      const half4v h = ses[j];
      const float f_[4] = {(float)h.x, (float)h.y, (float)h.z, (float)h.w};
#pragma unroll
      for (int q = 0; q < 4; ++q) {
        AR_SAMPLE(4 * j + q, f_[q], acc)
        (void)acc;
      }
    }
  }
  // Signal start: frame 0 must begin from the true zero state (warm-up
  // read clamped junk for Lf<=0 lanes).
  if (Lf <= 0) {
#pragma unroll
    for (int i = 0; i < 16; ++i) x[i] = 0.f;
  }
  float z = 0.f;  // zf: de-emph contribution of the emit frame alone
  __syncthreads();  // lane 64's warm-up reads slot 63 before its writeback

  // ---- Emit pass: AR + single-frame z, fp16 z written back in place
  // (own slot, read-before-write within each j).
  {
    half4v* __restrict__ ses = (half4v*)(s_e + tid * kSE);
    const float a_[15] = {e0.y, e0.z, e0.w, e1.x, e1.y, e1.z, e1.w,
                          e2.x, e2.y, e2.z, e2.w, e3.x, e3.y, e3.z, e3.w};
#pragma unroll
    for (int j = 0; j < 20; ++j) {
      const half4v h = ses[j];
      const float f_[4] = {(float)h.x, (float)h.y, (float)h.z, (float)h.w};
      half4v ho;
#pragma unroll
      for (int q = 0; q < 4; ++q) {
        AR_SAMPLE(4 * j + q, f_[q], acc)
        z = fmaf(kEmph, z, acc);  // de-emph over emit frame only
        if (q == 0) ho.x = (_Float16)z;
        if (q == 1) ho.y = (_Float16)z;
        if (q == 2) ho.z = (_Float16)z;
        if (q == 3) ho.w = (_Float16)z;
      }
      ses[j] = ho;
    }
  }
#undef AR_SAMPLE
  // zf=0 for frames outside the signal so correction guards vanish.
  s_zend[tid] = (Lf < 0 || Lf >= kF) ? 0.f : z;
  __syncthreads();

  // ---- Coalesced store + 4-term de-emph init correction.
  // Frame k (block-local, lane k+4): z_exact(s) = z_loc(s) + 0.97^(s+1)*Zp,
  //   Zp = zf[k+3] + r*zf[k+2] + r^2*zf[k+1] + r^3*zf[k]   (r = 0.97^80)
  // covering frames fbase+k-1 .. fbase+k-4; residual r^4*|Z|max ~ 1.3e-3.
  {
    const int nfr = min(kEmit, kF - fbase);  // valid frames this block
    const int nv4 = nfr * 20;
    vfloat4* __restrict__ ob =
        (vfloat4*)(out + (size_t)b * kL + (size_t)fbase * kFS);
#pragma unroll 1
    for (int i = tid; i < nv4; i += kThreads) {
      const int k = i / 20;  // frame within block -> LDS slot k+4
      const int j = i % 20;  // float4 within frame
      const half4v h = *(const half4v*)(s_e + (k + 4) * kSE + 4 * j);
      float Zp = s_zend[k + 3];
      Zp = fmaf(kR1, s_zend[k + 2], Zp);
      Zp = fmaf(kR2, s_zend[k + 1], Zp);
      Zp = fmaf(kR3, s_zend[k], Zp);
      const float ee = __builtin_exp2f(kLg97 * (float)(4 * j + 1));
      vfloat4 v;
      v.x = fmaf(ee, Zp, (float)h.x);
      v.y = fmaf(ee * 0.97f, Zp, (float)h.y);
      v.z = fmaf(ee * 0.9409f, Zp, (float)h.z);
      v.w = fmaf(ee * 0.912673f, Zp, (float)h.w);
      ob[i] = v;  // lane-consecutive float4s: full 1 KB bursts per wave
    }
  }
}

extern "C" void kernel_launch(void* const* d_in, const int* in_sizes, int n_in,
                              void* d_out, int out_size, void* d_ws,
                              size_t ws_size, hipStream_t stream) {
  const float* excit = (const float*)d_in[0];  // (B, L, 1) fp32
  const float* coef = (const float*)d_in[1];   // (B, F, 16) fp32
  float* out = (float*)d_out;                  // (B, L, 1) fp32

  dim3 grid((kF + kEmit - 1) / kEmit, kB);  // 25 x 64 blocks of 128
  lpc_synth_kernel<<<grid, kThreads, 0, stream>>>(excit, coef, out);
}

// Round 6
// 124.831 us; speedup vs baseline: 1.1436x; 1.0163x over previous
//
#include <hip/hip_runtime.h>

// LPC synthesis (AR(15), frame-hopped coefs) + de-emphasis IIR.
//
// R12: HALF-FRAME DECOMPOSITION. R11 measured 43 us with VALU-busy ~13 us,
// memory floor ~16 us, occupancy 21% -> stall-bound serial-phase chain with
// too few waves. Fix: one lane per 40-sample HALF-frame. Threads 2x (400K),
// emit serial length halves, grid 3264 blocks -> ~25 waves/CU launched,
// LDS 12.3 KB/block. Redundancy rises 1.6x->2.2x (warm 48 + emit 40) but
// spreads over 2x waves with ~2x residency.
//  - De-emph correction per half-frame: r = 0.97^40, 9-term Neumann
//    (residual r^9*|z|max ~ 4e-4), precomputed into s_zp (1 thread per
//    output half-frame) so the store loop reads it once.
//  - Warm-up = 48 samples: tail 8 of half-frame ht-2 (prev-frame taps) +
//    40 of ht-1 (prev taps if ht even, cur taps if odd -- one-time select).
//    Pre-signal samples MASKED to zero -> ht=0,1 lanes exact (replaces
//    the g<=0 reset).
// Error budget: fp16 z-writeback 2^-6 floor (measured R11 absmax exactly
// 0.015625) + correction 4e-4 + fp16 excit ~2e-3 + AR trunc rho^48 ->
// ~0.016-0.031 vs threshold 0.0456.
//
// Kept: R9 coalesced output (in-place fp16 z writeback + LDS store phase;
// R8 proved scattered 16B/lane stores write-amplify 2.6x at occupancy);
// R8 fp16 staging + fmaf(-a,..) neg-modifier tap folding; R11 tap-load
// hoist above staging; R3 no big per-lane arrays.

namespace {
constexpr int kFS = 80;         // frame shift
constexpr int kHS = 40;         // samples per half-frame
constexpr int kF = 3000;        // frames per batch
constexpr int kH = 2 * kF;      // 6000 half-frames per batch
constexpr int kL = kFS * kF;    // 240000
constexpr int kOrder = 16;
constexpr int kB = 64;
constexpr float kEmph = 0.97f;
constexpr int kThreads = 128;   // 2 waves/block
constexpr int kJunk = 9;        // 9-term correction needs 9 lead lanes
constexpr int kEmitH = kThreads - kJunk;  // 119 half-frames per block
constexpr int kSEH = 44;        // LDS halves per slot (88 B, 8B-aligned)
constexpr float kLg97 = -4.3943347e-2f;  // log2(0.97)
// powers of r = 0.97^40
constexpr float kR1 = 0.2957118f;
constexpr float kR2 = 0.08744547f;
constexpr float kR3 = 0.02585867f;
constexpr float kR4 = 0.00764671f;
constexpr float kR5 = 0.00226126f;
constexpr float kR6 = 6.6867e-4f;
constexpr float kR7 = 1.9773e-4f;
constexpr float kR8 = 5.8472e-5f;

typedef float vfloat4 __attribute__((ext_vector_type(4)));
typedef _Float16 half4v __attribute__((ext_vector_type(4)));
}  // namespace

__global__ __launch_bounds__(kThreads) void lpc_synth_kernel(
    const float* __restrict__ excit, const float* __restrict__ coef,
    float* __restrict__ out) {
  __shared__ _Float16 s_e[kThreads * kSEH];  // 11264 B
  __shared__ float s_zend[kThreads];         //   512 B: per-lane zh
  __shared__ float s_zp[kThreads];           //   512 B: per-output Zp

  const int tid = threadIdx.x;
  const int b = blockIdx.y;
  const int hbase = blockIdx.x * kEmitH;
  const int ht = hbase + tid - kJunk;  // half-frame this lane stages+emits
  const int hc = min(max(ht, 0), kH - 1);
  const int hw = min(max(ht - 2, 0), kH - 1);

  const float* __restrict__ ebase = excit + (size_t)b * kL;
  const float* __restrict__ cbase = coef + (size_t)b * kF * kOrder;

  // ---- Hoisted tap loads (prev frame for warm-up, cur frame for emit):
  // latency covered by the staging loads + barrier below.
  const int fprev = hw >> 1;
  const int fcur = hc >> 1;
  const vfloat4* __restrict__ cp =
      (const vfloat4*)(cbase + (size_t)fprev * kOrder);
  const vfloat4* __restrict__ cc =
      (const vfloat4*)(cbase + (size_t)fcur * kOrder);
  const vfloat4 p0 = cp[0], p1 = cp[1], p2 = cp[2], p3 = cp[3];
  const vfloat4 q0 = cc[0], q1 = cc[1], q2 = cc[2], q3 = cc[3];

  // ---- Stage own half-frame as fp16 (10 x 16B loads -> 8B writes).
  {
    const vfloat4* __restrict__ ep =
        (const vfloat4*)(ebase + (size_t)hc * kHS);
    half4v* se = (half4v*)(s_e + tid * kSEH);
#pragma unroll
    for (int j = 0; j < 10; ++j) {
      const vfloat4 v = ep[j];
      half4v h;
      h.x = (_Float16)v.x;
      h.y = (_Float16)v.y;
      h.z = (_Float16)v.z;
      h.w = (_Float16)v.w;
      se[j] = h;
    }
  }
  __syncthreads();

  // Ring buffer of last 16 y-samples, local counter s (warm 0..47 then
  // emit 48..87; compile-time indexed -> VGPRs). x starts 0 = pre-warm
  // state assumption; truncation rho^48.
  float x[16];
#pragma unroll
  for (int i = 0; i < 16; ++i) x[i] = 0.f;

  float pa_[15] = {p0.y, p0.z, p0.w, p1.x, p1.y, p1.z, p1.w,
                   p2.x, p2.y, p2.z, p2.w, p3.x, p3.y, p3.z, p3.w};
  const float ca_[15] = {q0.y, q0.z, q0.w, q1.x, q1.y, q1.z, q1.w,
                         q2.x, q2.y, q2.z, q2.w, q3.x, q3.y, q3.z, q3.w};

  // One AR sample; 3 partial accumulators keep the cross-sample critical
  // path at 1 fma + 1 add (8 cyc). Taps consumed as -A[k] via the fmaf
  // neg source modifier (zero cost).
#define AR_SAMPLE(A, s, e_in, ACC)                                         \
  float ACC;                                                               \
  {                                                                        \
    float t0 = (e_in);                                                     \
    t0 = fmaf(-A[14], x[((s)-15) & 15], t0);                               \
    t0 = fmaf(-A[13], x[((s)-14) & 15], t0);                               \
    t0 = fmaf(-A[12], x[((s)-13) & 15], t0);                               \
    t0 = fmaf(-A[11], x[((s)-12) & 15], t0);                               \
    t0 = fmaf(-A[10], x[((s)-11) & 15], t0);                               \
    float t1 = -A[9] * x[((s)-10) & 15];                                   \
    t1 = fmaf(-A[8], x[((s)-9) & 15], t1);                                 \
    t1 = fmaf(-A[7], x[((s)-8) & 15], t1);                                 \
    t1 = fmaf(-A[6], x[((s)-7) & 15], t1);                                 \
    t1 = fmaf(-A[5], x[((s)-6) & 15], t1);                                 \
    float t2 = -A[4] * x[((s)-5) & 15];                                    \
    t2 = fmaf(-A[3], x[((s)-4) & 15], t2);                                 \
    t2 = fmaf(-A[2], x[((s)-3) & 15], t2);                                 \
    t2 = fmaf(-A[1], x[((s)-2) & 15], t2);                                 \
    const float t01 = t0 + t1;               /* off critical path */       \
    t2 = fmaf(-A[0], x[((s)-1) & 15], t2);   /* critical: 1 fma */         \
    ACC = t01 + t2;                          /* + 1 add */                 \
    x[(s)&15] = ACC;                                                       \
  }

  // ---- AR-only warm-up: 48 samples before emit start.
  {
    const half4v* __restrict__ s2 =
        (const half4v*)(s_e + max(tid - 2, 0) * kSEH);
    const half4v* __restrict__ s1 =
        (const half4v*)(s_e + max(tid - 1, 0) * kSEH);
    const float m2 = (ht >= 2) ? 1.f : 0.f;  // pre-signal inputs -> 0
    const float m1 = (ht >= 1) ? 1.f : 0.f;
    // Samples 0..7: tail (32..39) of half-frame ht-2, prev-frame taps.
#pragma unroll
    for (int j = 0; j < 2; ++j) {
      const half4v h = s2[8 + j];
      const float f_[4] = {m2 * (float)h.x, m2 * (float)h.y,
                           m2 * (float)h.z, m2 * (float)h.w};
#pragma unroll
      for (int q = 0; q < 4; ++q) {
        AR_SAMPLE(pa_, 4 * j + q, f_[q], acc)
        (void)acc;
      }
    }
    // Half-frame ht-1 belongs to frame fcur when ht is odd, fprev when
    // even: one-time tap select (15 cndmask), masked lanes don't care.
    if (ht & 1) {
#pragma unroll
      for (int k = 0; k < 15; ++k) pa_[k] = ca_[k];
    }
    // Samples 8..47: half-frame ht-1 in full.
#pragma unroll
    for (int j = 0; j < 10; ++j) {
      const half4v h = s1[j];
      const float f_[4] = {m1 * (float)h.x, m1 * (float)h.y,
                           m1 * (float)h.z, m1 * (float)h.w};
#pragma unroll
      for (int q = 0; q < 4; ++q) {
        AR_SAMPLE(pa_, 8 + 4 * j + q, f_[q], acc)
        (void)acc;
      }
    }
  }

  float z = 0.f;  // zh: de-emph contribution of this half-frame alone
  // Cross-wave hazard: wave-1 lanes read slots 62,63 in warm-up; those
  // lanes' emit writebacks must wait.
  __syncthreads();

  // ---- Emit pass: AR + half-frame-local z, fp16 z written back in place
  // (own slot, read-before-write within each j).
  {
    half4v* __restrict__ ses = (half4v*)(s_e + tid * kSEH);
#pragma unroll
    for (int j = 0; j < 10; ++j) {
      const half4v h = ses[j];
      const float f_[4] = {(float)h.x, (float)h.y, (float)h.z, (float)h.w};
      half4v ho;
#pragma unroll
      for (int q = 0; q < 4; ++q) {
        AR_SAMPLE(ca_, 48 + 4 * j + q, f_[q], acc)
        z = fmaf(kEmph, z, acc);
        if (q == 0) ho.x = (_Float16)z;
        if (q == 1) ho.y = (_Float16)z;
        if (q == 2) ho.z = (_Float16)z;
        if (q == 3) ho.w = (_Float16)z;
      }
      ses[j] = ho;
    }
  }
#undef AR_SAMPLE
  // zh=0 outside the signal so correction terms vanish automatically.
  s_zend[tid] = (ht < 0 || ht >= kH) ? 0.f : z;
  __syncthreads();

  // ---- Per-output-half-frame de-emph init (9-term Neumann, r=0.97^40):
  // output k (block-local, lane k+9): Zp = sum_{i=1..9} r^(i-1)*zh[k+9-i].
  if (tid < kEmitH) {
    float Zp = s_zend[tid + 8];
    Zp = fmaf(kR1, s_zend[tid + 7], Zp);
    Zp = fmaf(kR2, s_zend[tid + 6], Zp);
    Zp = fmaf(kR3, s_zend[tid + 5], Zp);
    Zp = fmaf(kR4, s_zend[tid + 4], Zp);
    Zp = fmaf(kR5, s_zend[tid + 3], Zp);
    Zp = fmaf(kR6, s_zend[tid + 2], Zp);
    Zp = fmaf(kR7, s_zend[tid + 1], Zp);
    Zp = fmaf(kR8, s_zend[tid + 0], Zp);
    s_zp[tid] = Zp;
  }
  __syncthreads();

  // ---- Coalesced store + correction: z_exact(s) = z_loc(s) + 0.97^(s+1)*Zp.
  // Lane-consecutive float4s: full 1 KB bursts per wave (R8/R9 lesson).
  {
    const int nfr = min(kEmitH, kH - hbase);  // valid half-frames
    const int nv4 = nfr * 10;
    vfloat4* __restrict__ ob =
        (vfloat4*)(out + (size_t)b * kL + (size_t)hbase * kHS);
#pragma unroll 1
    for (int i = tid; i < nv4; i += kThreads) {
      const int k = i / 10;  // half-frame within block -> LDS slot k+9
      const int j = i % 10;  // float4 within half-frame
      const half4v h = *(const half4v*)(s_e + (k + kJunk) * kSEH + 4 * j);
      const float Zp = s_zp[k];
      const float ee = __builtin_exp2f(kLg97 * (float)(4 * j + 1));
      vfloat4 v;
      v.x = fmaf(ee, Zp, (float)h.x);
      v.y = fmaf(ee * 0.97f, Zp, (float)h.y);
      v.z = fmaf(ee * 0.9409f, Zp, (float)h.z);
      v.w = fmaf(ee * 0.912673f, Zp, (float)h.w);
      ob[i] = v;
    }
  }
}

extern "C" void kernel_launch(void* const* d_in, const int* in_sizes, int n_in,
                              void* d_out, int out_size, void* d_ws,
                              size_t ws_size, hipStream_t stream) {
  const float* excit = (const float*)d_in[0];  // (B, L, 1) fp32
  const float* coef = (const float*)d_in[1];   // (B, F, 16) fp32
  float* out = (float*)d_out;                  // (B, L, 1) fp32

  dim3 grid((kH + kEmitH - 1) / kEmitH, kB);  // 51 x 64 blocks of 128
  lpc_synth_kernel<<<grid, kThreads, 0, stream>>>(excit, coef, out);
}